// Round 1
// baseline (852.255 us; speedup 1.0000x reference)
//
#include <hip/hip_runtime.h>
#include <hip/hip_bf16.h>

// Problem constants: B=4, N=4096, C=1024, H=16, d=64
#define BB 4
#define NN 4096
#define CC 1024
#define HH 16
#define DD 64
#define MM (BB*NN)          // 16384 rows of tokens
#define EPSF 1e-6f

typedef __bf16 bf16x8 __attribute__((ext_vector_type(8)));
typedef float f32x4 __attribute__((ext_vector_type(4)));

__device__ __forceinline__ void gload_lds16(const void* g, void* l) {
    __builtin_amdgcn_global_load_lds(
        (const __attribute__((address_space(1))) void*)g,
        (__attribute__((address_space(3))) void*)l, 16, 0, 0);
}

// ---------------------------------------------------------------------------
// split fp32 -> bf16 hi + bf16 lo
__global__ __launch_bounds__(256)
void split_kernel(const float* __restrict__ src, __bf16* __restrict__ hi,
                  __bf16* __restrict__ lo, int n)
{
    int i = blockIdx.x * 256 + threadIdx.x;
    if (i < n) {
        float f = src[i];
        __bf16 h = (__bf16)f;
        hi[i] = h;
        lo[i] = (__bf16)(f - (float)h);
    }
}

// ---------------------------------------------------------------------------
// 128x128-tile bf16 MFMA GEMM, A (M x 1024) bf16, B^T layout (Ncols x 1024) bf16,
// 3 K-segments accumulated (hi/lo split products).
// EPI 0: focused-feature epilogue -> fp16 F ; EPI 1: +bias -> fp32 out
template<int EPI>
__global__ __launch_bounds__(256)
void gemm_bt(const __bf16* __restrict__ A0, const __bf16* __restrict__ A1,
             const __bf16* __restrict__ A2,
             const __bf16* __restrict__ B0, const __bf16* __restrict__ B1,
             const __bf16* __restrict__ B2,
             void* __restrict__ Cout, const float* __restrict__ bias, int Ncols)
{
    __shared__ __bf16 As[128 * 32];
    __shared__ __bf16 Bs[128 * 32];

    const int tid  = threadIdx.x;
    const int lane = tid & 63;
    const int wid  = tid >> 6;          // 0..3
    const int wr   = wid >> 1;          // wave row (0..1)
    const int wc   = wid & 1;           // wave col (0..1)
    const int brow = blockIdx.y * 128;
    const int bcol = blockIdx.x * 128;

    f32x4 acc[4][4] = {};

    const __bf16* Aseg[3] = {A0, A1, A2};
    const __bf16* Bseg[3] = {B0, B1, B2};

    const int srow  = lane >> 2;        // 0..15
    const int skoff = (lane & 3) * 8;   // bf16 elems within K-step

    const int arow = wr * 64 + (lane & 15);
    const int brw  = wc * 64 + (lane & 15);
    const int acol = (lane >> 4) * 8;

#pragma unroll
    for (int s = 0; s < 3; ++s) {
        const __bf16* Ab = Aseg[s];
        const __bf16* Bb = Bseg[s];
        for (int kt = 0; kt < 1024; kt += 32) {
#pragma unroll
            for (int i = 0; i < 2; ++i) {
                int rg = (wid * 2 + i);                 // 0..7 : 16-row group
                int r  = rg * 16 + srow;
                gload_lds16(Ab + (size_t)(brow + r) * 1024 + kt + skoff,
                            (char*)As + rg * 1024);
                gload_lds16(Bb + (size_t)(bcol + r) * 1024 + kt + skoff,
                            (char*)Bs + rg * 1024);
            }
            __syncthreads();
            bf16x8 af[4], bfr[4];
#pragma unroll
            for (int m = 0; m < 4; ++m)
                af[m] = *(const bf16x8*)&As[(arow + m * 16) * 32 + acol];
#pragma unroll
            for (int n = 0; n < 4; ++n)
                bfr[n] = *(const bf16x8*)&Bs[(brw + n * 16) * 32 + acol];
#pragma unroll
            for (int m = 0; m < 4; ++m)
#pragma unroll
                for (int n = 0; n < 4; ++n)
                    acc[m][n] = __builtin_amdgcn_mfma_f32_16x16x32_bf16(
                        af[m], bfr[n], acc[m][n], 0, 0, 0);
            __syncthreads();
        }
    }

    // Epilogue.  D layout: col = lane&15 (+n*16), row = (lane>>4)*4 + reg (+m*16)
    if (EPI == 0) {
        _Float16* F = (_Float16*)Cout;
        const bool feat = (bcol < 2048);   // q and k sections get the feature map
#pragma unroll
        for (int m = 0; m < 4; ++m) {
            int rbase = brow + wr * 64 + m * 16 + (lane >> 4) * 4;
#pragma unroll
            for (int r = 0; r < 4; ++r) {
                float u3[4];
                float ssum = 0.f;
#pragma unroll
                for (int n = 0; n < 4; ++n) {
                    float v = acc[m][n][r];
                    if (feat) {
                        float u = fmaxf(v, 0.f) + EPSF;
                        float c = u * u * u;
                        u3[n] = c; ssum += c;
                    } else {
                        u3[n] = v;
                    }
                }
                if (feat) {
                    ssum += __shfl_xor(ssum, 1, 16);
                    ssum += __shfl_xor(ssum, 2, 16);
                    ssum += __shfl_xor(ssum, 4, 16);
                    ssum += __shfl_xor(ssum, 8, 16);
                    float inv = 1.0f / ssum;
#pragma unroll
                    for (int n = 0; n < 4; ++n) u3[n] *= inv;
                }
                size_t base = (size_t)(rbase + r) * Ncols + bcol + wc * 64 + (lane & 15);
#pragma unroll
                for (int n = 0; n < 4; ++n)
                    F[base + n * 16] = (_Float16)u3[n];
            }
        }
    } else {
        float* Oc = (float*)Cout;
#pragma unroll
        for (int m = 0; m < 4; ++m) {
            int rbase = brow + wr * 64 + m * 16 + (lane >> 4) * 4;
#pragma unroll
            for (int r = 0; r < 4; ++r) {
                size_t base = (size_t)(rbase + r) * Ncols + bcol + wc * 64 + (lane & 15);
#pragma unroll
                for (int n = 0; n < 4; ++n)
                    Oc[base + n * 16] = acc[m][n][r] + bias[bcol + wc * 64 + n * 16 + (lane & 15)];
            }
        }
    }
}

// ---------------------------------------------------------------------------
// kv[b,h,dk,dv] = sum_n kf[b,n,h,dk] * v[b,n,h,dv] ; ksum[b,h,dk] = sum_n kf
__global__ __launch_bounds__(256)
void kv_kernel(const _Float16* __restrict__ F, float* __restrict__ kv,
               float* __restrict__ ksum)
{
    int bh = blockIdx.y;                 // 0..63
    int b = bh >> 4, h = bh & 15;
    int seg = blockIdx.x;                // 0..7 over n
    int t = threadIdx.x;
    __shared__ float kf[64][65];
    __shared__ float vf[64][64];
    float acc[16] = {};
    float ks = 0.f;
    int dv = t & 63, dkb = (t >> 6) * 16;
    const _Float16* Fk = F + (size_t)(b * NN) * 3072 + 1024 + h * 64;
    const _Float16* Fv = F + (size_t)(b * NN) * 3072 + 2048 + h * 64;

    for (int tile = 0; tile < 8; ++tile) {
        int n0 = seg * 512 + tile * 64;
        __syncthreads();
#pragma unroll
        for (int i = 0; i < 16; ++i) {
            int idx = t + i * 256;
            int tok = idx >> 6, dd = idx & 63;
            size_t off = (size_t)(n0 + tok) * 3072 + dd;
            kf[tok][dd] = (float)Fk[off];
            vf[tok][dd] = (float)Fv[off];
        }
        __syncthreads();
        for (int n = 0; n < 64; ++n) {
            float vv = vf[n][dv];
#pragma unroll
            for (int i = 0; i < 16; ++i)
                acc[i] += kf[n][dkb + i] * vv;
        }
        if (t < 64) {
            for (int n = 0; n < 64; ++n) ks += kf[n][t];
        }
    }
#pragma unroll
    for (int i = 0; i < 16; ++i)
        atomicAdd(&kv[((size_t)bh * 64 + dkb + i) * 64 + dv], acc[i]);
    if (t < 64) atomicAdd(&ksum[bh * 64 + t], ks);
}

// ---------------------------------------------------------------------------
// y0[b,n,h*64+dv] = (sum_dk qf[b,n,h,dk]*kv[b,h,dk,dv]) * z[b,h,n]
__global__ __launch_bounds__(256)
void attn_kernel(const _Float16* __restrict__ F, const float* __restrict__ kv,
                 const float* __restrict__ ksum, float* __restrict__ y0)
{
    int h = blockIdx.x;                  // 0..15
    int cb = blockIdx.y;                 // 0..255
    int b = cb >> 6, chunk = cb & 63;
    int n0 = chunk * 64;
    int t = threadIdx.x;
    int bh = b * HH + h;
    __shared__ float qf[64][65];
    __shared__ float kvs[64 * 64];
    __shared__ float ksm[64];
    __shared__ float zz[64];
    const _Float16* Fq = F + (size_t)(b * NN + n0) * 3072 + h * 64;
#pragma unroll
    for (int i = 0; i < 16; ++i) {
        int idx = t + i * 256;
        int tok = idx >> 6, dd = idx & 63;
        qf[tok][dd] = (float)Fq[(size_t)tok * 3072 + dd];
        kvs[idx] = kv[(size_t)bh * 4096 + idx];
    }
    if (t < 64) ksm[t] = ksum[bh * 64 + t];
    __syncthreads();
    if (t < 64) {
        float s = 0.f;
        for (int dk = 0; dk < 64; ++dk) s += qf[t][dk] * ksm[dk];
        zz[t] = 1.0f / (s + EPSF);
    }
    __syncthreads();
    int dv = t & 63, nb = t >> 6;
#pragma unroll 4
    for (int i = 0; i < 16; ++i) {
        int nl = nb * 16 + i;
        float a = 0.f;
        for (int dk = 0; dk < 64; ++dk)
            a += qf[nl][dk] * kvs[dk * 64 + dv];
        y0[(size_t)(b * NN + n0 + nl) * CC + h * 64 + dv] = a * zz[nl];
    }
}

// ---------------------------------------------------------------------------
// y = y0 + dwconv3(y0) + b_dwc ; split into bf16 hi/lo for proj GEMM
__global__ __launch_bounds__(256)
void conv_kernel(const float* __restrict__ y0, const float* __restrict__ wdwc,
                 const float* __restrict__ bdwc, __bf16* __restrict__ yh,
                 __bf16* __restrict__ yl)
{
    int gid = blockIdx.x * 256 + threadIdx.x;
    int m = gid >> 8;                    // token row 0..16383
    int c0 = (gid & 255) * 4;
    int n = m & (NN - 1);
    const float* P = y0 + (size_t)m * CC;
    float4 cur = *(const float4*)(P + c0);
    float4 prv = make_float4(0.f, 0.f, 0.f, 0.f);
    float4 nxt = make_float4(0.f, 0.f, 0.f, 0.f);
    if (n > 0)      prv = *(const float4*)(P - CC + c0);
    if (n < NN - 1) nxt = *(const float4*)(P + CC + c0);
    float cu[4] = {cur.x, cur.y, cur.z, cur.w};
    float pv[4] = {prv.x, prv.y, prv.z, prv.w};
    float nx[4] = {nxt.x, nxt.y, nxt.z, nxt.w};
#pragma unroll
    for (int j = 0; j < 4; ++j) {
        int c = c0 + j;
        float w0 = wdwc[c * 3 + 0], w1 = wdwc[c * 3 + 1], w2 = wdwc[c * 3 + 2];
        float val = cu[j] + pv[j] * w0 + cu[j] * w1 + nx[j] * w2 + bdwc[c];
        __bf16 hb = (__bf16)val;
        yh[(size_t)m * CC + c] = hb;
        yl[(size_t)m * CC + c] = (__bf16)(val - (float)hb);
    }
}

// ---------------------------------------------------------------------------
extern "C" void kernel_launch(void* const* d_in, const int* in_sizes, int n_in,
                              void* d_out, int out_size, void* d_ws, size_t ws_size,
                              hipStream_t stream)
{
    const float* x      = (const float*)d_in[0];
    const float* w_qkv  = (const float*)d_in[1];
    const float* w_proj = (const float*)d_in[2];
    const float* b_proj = (const float*)d_in[3];
    const float* w_dwc  = (const float*)d_in[4];
    const float* b_dwc  = (const float*)d_in[5];
    float* out = (float*)d_out;

    char* p = (char*)d_ws;
    __bf16* xh  = (__bf16*)p;  p += (size_t)MM * CC * 2;        // 33.5 MB
    __bf16* xl  = (__bf16*)p;  p += (size_t)MM * CC * 2;        // 33.5 MB
    __bf16* wqh = (__bf16*)p;  p += (size_t)3 * CC * CC * 2;    // 6.3 MB
    __bf16* wql = (__bf16*)p;  p += (size_t)3 * CC * CC * 2;
    __bf16* wph = (__bf16*)p;  p += (size_t)CC * CC * 2;        // 2.1 MB
    __bf16* wpl = (__bf16*)p;  p += (size_t)CC * CC * 2;
    _Float16* F = (_Float16*)p; p += (size_t)MM * 3 * CC * 2;   // 100.7 MB
    float* kvb  = (float*)p;   p += (size_t)BB * HH * 64 * 64 * 4; // 1 MB
    float* ksum = (float*)p;   p += (size_t)BB * HH * 64 * 4;      // 16 KB
    float* y0   = (float*)p;   p += (size_t)MM * CC * 4;        // 67 MB

    // 1. split inputs to bf16 hi/lo
    split_kernel<<<(MM * CC + 255) / 256, 256, 0, stream>>>(x, xh, xl, MM * CC);
    split_kernel<<<(3 * CC * CC + 255) / 256, 256, 0, stream>>>(w_qkv, wqh, wql, 3 * CC * CC);
    split_kernel<<<(CC * CC + 255) / 256, 256, 0, stream>>>(w_proj, wph, wpl, CC * CC);

    // 2. QKV GEMM with fused focused-feature epilogue -> F (fp16)
    gemm_bt<0><<<dim3(3 * CC / 128, MM / 128), 256, 0, stream>>>(
        xh, xh, xl, wqh, wql, wqh, (void*)F, nullptr, 3 * CC);

    // 3. kv / ksum accumulation
    hipMemsetAsync(kvb, 0, (size_t)(BB * HH * 64 * 64 + BB * HH * 64) * 4, stream);
    kv_kernel<<<dim3(8, BB * HH), 256, 0, stream>>>(F, kvb, ksum);

    // 4. attention output
    attn_kernel<<<dim3(HH, BB * (NN / 64)), 256, 0, stream>>>(F, kvb, ksum, y0);

    // 5. depthwise conv + residual, re-split to bf16 (reuse xh/xl buffers)
    conv_kernel<<<MM, 256, 0, stream>>>(y0, w_dwc, b_dwc, xh, xl);

    // 6. output projection + bias
    gemm_bt<1><<<dim3(CC / 128, MM / 128), 256, 0, stream>>>(
        xh, xh, xl, wph, wpl, wph, d_out, b_proj, CC);
}

// Round 2
// 473.660 us; speedup vs baseline: 1.7993x; 1.7993x over previous
//
#include <hip/hip_runtime.h>
#include <hip/hip_bf16.h>

// Problem constants: B=4, N=4096, C=1024, H=16, d=64
#define BB 4
#define NN 4096
#define CC 1024
#define HH 16
#define DD 64
#define MM (BB*NN)          // 16384 rows of tokens
#define EPSF 1e-6f

typedef _Float16 f16x8 __attribute__((ext_vector_type(8)));
typedef float f32x4 __attribute__((ext_vector_type(4)));

__device__ __forceinline__ void gload_lds16(const void* g, void* l) {
    __builtin_amdgcn_global_load_lds(
        (const __attribute__((address_space(1))) void*)g,
        (__attribute__((address_space(3))) void*)l, 16, 0, 0);
}

// ---------------------------------------------------------------------------
// fp32 -> fp16, 4 elems/thread
__global__ __launch_bounds__(256)
void tofp16_kernel(const float* __restrict__ src, _Float16* __restrict__ dst, int n4)
{
    int i = blockIdx.x * 256 + threadIdx.x;
    if (i < n4) {
        float4 f = ((const float4*)src)[i];
        _Float16 h0 = (_Float16)f.x, h1 = (_Float16)f.y;
        _Float16 h2 = (_Float16)f.z, h3 = (_Float16)f.w;
        short4 pk;
        pk.x = __builtin_bit_cast(short, h0);
        pk.y = __builtin_bit_cast(short, h1);
        pk.z = __builtin_bit_cast(short, h2);
        pk.w = __builtin_bit_cast(short, h3);
        ((short4*)dst)[i] = pk;
    }
}

// ---------------------------------------------------------------------------
// 128x128-tile fp16 MFMA GEMM. A (M x 1024) fp16, B^T layout (Ncols x 1024) fp16.
// EPI 0: focused-feature epilogue -> fp16 F ; EPI 1: +bias -> fp32 out
template<int EPI>
__global__ __launch_bounds__(256)
void gemm_bt(const _Float16* __restrict__ A, const _Float16* __restrict__ B,
             void* __restrict__ Cout, const float* __restrict__ bias, int Ncols)
{
    __shared__ _Float16 As[128 * 32];
    __shared__ _Float16 Bs[128 * 32];

    const int tid  = threadIdx.x;
    const int lane = tid & 63;
    const int wid  = tid >> 6;          // 0..3
    const int wr   = wid >> 1;          // wave row (0..1)
    const int wc   = wid & 1;           // wave col (0..1)
    const int brow = blockIdx.y * 128;
    const int bcol = blockIdx.x * 128;

    f32x4 acc[4][4] = {};

    const int srow  = lane >> 2;        // 0..15
    const int skoff = (lane & 3) * 8;   // fp16 elems within K-step

    const int arow = wr * 64 + (lane & 15);
    const int brw  = wc * 64 + (lane & 15);
    const int acol = (lane >> 4) * 8;

    for (int kt = 0; kt < 1024; kt += 32) {
#pragma unroll
        for (int i = 0; i < 2; ++i) {
            int rg = (wid * 2 + i);                 // 0..7 : 16-row group
            int r  = rg * 16 + srow;
            gload_lds16(A + (size_t)(brow + r) * 1024 + kt + skoff,
                        (char*)As + rg * 1024);
            gload_lds16(B + (size_t)(bcol + r) * 1024 + kt + skoff,
                        (char*)Bs + rg * 1024);
        }
        __syncthreads();
        f16x8 af[4], bfr[4];
#pragma unroll
        for (int m = 0; m < 4; ++m)
            af[m] = *(const f16x8*)&As[(arow + m * 16) * 32 + acol];
#pragma unroll
        for (int n = 0; n < 4; ++n)
            bfr[n] = *(const f16x8*)&Bs[(brw + n * 16) * 32 + acol];
#pragma unroll
        for (int m = 0; m < 4; ++m)
#pragma unroll
            for (int n = 0; n < 4; ++n)
                acc[m][n] = __builtin_amdgcn_mfma_f32_16x16x32_f16(
                    af[m], bfr[n], acc[m][n], 0, 0, 0);
        __syncthreads();
    }

    // Epilogue.  D layout: col = lane&15 (+n*16), row = (lane>>4)*4 + reg (+m*16)
    if (EPI == 0) {
        _Float16* F = (_Float16*)Cout;
        const bool feat = (bcol < 2048);   // q and k sections get the feature map
#pragma unroll
        for (int m = 0; m < 4; ++m) {
            int rbase = brow + wr * 64 + m * 16 + (lane >> 4) * 4;
#pragma unroll
            for (int r = 0; r < 4; ++r) {
                float u3[4];
                float ssum = 0.f;
#pragma unroll
                for (int n = 0; n < 4; ++n) {
                    float v = acc[m][n][r];
                    if (feat) {
                        float u = fmaxf(v, 0.f) + EPSF;
                        float c = u * u * u;
                        u3[n] = c; ssum += c;
                    } else {
                        u3[n] = v;
                    }
                }
                if (feat) {
                    ssum += __shfl_xor(ssum, 1, 16);
                    ssum += __shfl_xor(ssum, 2, 16);
                    ssum += __shfl_xor(ssum, 4, 16);
                    ssum += __shfl_xor(ssum, 8, 16);
                    float inv = 1.0f / ssum;
#pragma unroll
                    for (int n = 0; n < 4; ++n) u3[n] *= inv;
                }
                size_t base = (size_t)(rbase + r) * Ncols + bcol + wc * 64 + (lane & 15);
#pragma unroll
                for (int n = 0; n < 4; ++n)
                    F[base + n * 16] = (_Float16)u3[n];
            }
        }
    } else {
        float* Oc = (float*)Cout;
#pragma unroll
        for (int m = 0; m < 4; ++m) {
            int rbase = brow + wr * 64 + m * 16 + (lane >> 4) * 4;
#pragma unroll
            for (int r = 0; r < 4; ++r) {
                size_t base = (size_t)(rbase + r) * Ncols + bcol + wc * 64 + (lane & 15);
#pragma unroll
                for (int n = 0; n < 4; ++n)
                    Oc[base + n * 16] = acc[m][n][r] + bias[bcol + wc * 64 + n * 16 + (lane & 15)];
            }
        }
    }
}

// ---------------------------------------------------------------------------
// kv[b,h,dk,dv] = sum_n kf[b,n,h,dk] * v[b,n,h,dv] ; ksum[b,h,dk] = sum_n kf
__global__ __launch_bounds__(256)
void kv_kernel(const _Float16* __restrict__ F, float* __restrict__ kv,
               float* __restrict__ ksum)
{
    int bh = blockIdx.y;                 // 0..63
    int b = bh >> 4, h = bh & 15;
    int seg = blockIdx.x;                // 0..7 over n
    int t = threadIdx.x;
    __shared__ float kf[64][65];
    __shared__ float vf[64][64];
    float acc[16] = {};
    float ks = 0.f;
    int dv = t & 63, dkb = (t >> 6) * 16;
    const _Float16* Fk = F + (size_t)(b * NN) * 3072 + 1024 + h * 64;
    const _Float16* Fv = F + (size_t)(b * NN) * 3072 + 2048 + h * 64;

    for (int tile = 0; tile < 8; ++tile) {
        int n0 = seg * 512 + tile * 64;
        __syncthreads();
#pragma unroll
        for (int i = 0; i < 16; ++i) {
            int idx = t + i * 256;
            int tok = idx >> 6, dd = idx & 63;
            size_t off = (size_t)(n0 + tok) * 3072 + dd;
            kf[tok][dd] = (float)Fk[off];
            vf[tok][dd] = (float)Fv[off];
        }
        __syncthreads();
        for (int n = 0; n < 64; ++n) {
            float vv = vf[n][dv];
#pragma unroll
            for (int i = 0; i < 16; ++i)
                acc[i] += kf[n][dkb + i] * vv;
        }
        if (t < 64) {
            for (int n = 0; n < 64; ++n) ks += kf[n][t];
        }
    }
#pragma unroll
    for (int i = 0; i < 16; ++i)
        atomicAdd(&kv[((size_t)bh * 64 + dkb + i) * 64 + dv], acc[i]);
    if (t < 64) atomicAdd(&ksum[bh * 64 + t], ks);
}

// ---------------------------------------------------------------------------
// y0[b,n,h*64+dv] = (sum_dk qf[b,n,h,dk]*kv[b,h,dk,dv]) * z[b,h,n]
__global__ __launch_bounds__(256)
void attn_kernel(const _Float16* __restrict__ F, const float* __restrict__ kv,
                 const float* __restrict__ ksum, float* __restrict__ y0)
{
    int h = blockIdx.x;                  // 0..15
    int cb = blockIdx.y;                 // 0..255
    int b = cb >> 6, chunk = cb & 63;
    int n0 = chunk * 64;
    int t = threadIdx.x;
    int bh = b * HH + h;
    __shared__ float qf[64][65];
    __shared__ float kvs[64 * 64];
    __shared__ float ksm[64];
    __shared__ float zz[64];
    const _Float16* Fq = F + (size_t)(b * NN + n0) * 3072 + h * 64;
#pragma unroll
    for (int i = 0; i < 16; ++i) {
        int idx = t + i * 256;
        int tok = idx >> 6, dd = idx & 63;
        qf[tok][dd] = (float)Fq[(size_t)tok * 3072 + dd];
        kvs[idx] = kv[(size_t)bh * 4096 + idx];
    }
    if (t < 64) ksm[t] = ksum[bh * 64 + t];
    __syncthreads();
    if (t < 64) {
        float s = 0.f;
        for (int dk = 0; dk < 64; ++dk) s += qf[t][dk] * ksm[dk];
        zz[t] = 1.0f / (s + EPSF);
    }
    __syncthreads();
    int dv = t & 63, nb = t >> 6;
#pragma unroll 4
    for (int i = 0; i < 16; ++i) {
        int nl = nb * 16 + i;
        float a = 0.f;
        for (int dk = 0; dk < 64; ++dk)
            a += qf[nl][dk] * kvs[dk * 64 + dv];
        y0[(size_t)(b * NN + n0 + nl) * CC + h * 64 + dv] = a * zz[nl];
    }
}

// ---------------------------------------------------------------------------
// y = y0 + dwconv3(y0) + b_dwc ; to fp16 for proj GEMM
__global__ __launch_bounds__(256)
void conv_kernel(const float* __restrict__ y0, const float* __restrict__ wdwc,
                 const float* __restrict__ bdwc, _Float16* __restrict__ yf)
{
    int gid = blockIdx.x * 256 + threadIdx.x;
    int m = gid >> 8;                    // token row 0..16383
    int c0 = (gid & 255) * 4;
    int n = m & (NN - 1);
    const float* P = y0 + (size_t)m * CC;
    float4 cur = *(const float4*)(P + c0);
    float4 prv = make_float4(0.f, 0.f, 0.f, 0.f);
    float4 nxt = make_float4(0.f, 0.f, 0.f, 0.f);
    if (n > 0)      prv = *(const float4*)(P - CC + c0);
    if (n < NN - 1) nxt = *(const float4*)(P + CC + c0);
    float cu[4] = {cur.x, cur.y, cur.z, cur.w};
    float pv[4] = {prv.x, prv.y, prv.z, prv.w};
    float nx[4] = {nxt.x, nxt.y, nxt.z, nxt.w};
    short4 pk;
    short* pks = (short*)&pk;
#pragma unroll
    for (int j = 0; j < 4; ++j) {
        int c = c0 + j;
        float w0 = wdwc[c * 3 + 0], w1 = wdwc[c * 3 + 1], w2 = wdwc[c * 3 + 2];
        float val = cu[j] + pv[j] * w0 + cu[j] * w1 + nx[j] * w2 + bdwc[c];
        _Float16 h = (_Float16)val;
        pks[j] = __builtin_bit_cast(short, h);
    }
    ((short4*)(yf + (size_t)m * CC))[gid & 255] = pk;
}

// ---------------------------------------------------------------------------
extern "C" void kernel_launch(void* const* d_in, const int* in_sizes, int n_in,
                              void* d_out, int out_size, void* d_ws, size_t ws_size,
                              hipStream_t stream)
{
    const float* x      = (const float*)d_in[0];
    const float* w_qkv  = (const float*)d_in[1];
    const float* w_proj = (const float*)d_in[2];
    const float* b_proj = (const float*)d_in[3];
    const float* w_dwc  = (const float*)d_in[4];
    const float* b_dwc  = (const float*)d_in[5];

    char* p = (char*)d_ws;
    _Float16* xf  = (_Float16*)p;  p += (size_t)MM * CC * 2;        // 33.5 MB
    _Float16* wqf = (_Float16*)p;  p += (size_t)3 * CC * CC * 2;    // 6.3 MB
    _Float16* wpf = (_Float16*)p;  p += (size_t)CC * CC * 2;        // 2.1 MB
    _Float16* F   = (_Float16*)p;  p += (size_t)MM * 3 * CC * 2;    // 100.7 MB
    float* kvb    = (float*)p;     p += (size_t)BB * HH * 64 * 64 * 4; // 1 MB
    float* ksum   = (float*)p;     p += (size_t)BB * HH * 64 * 4;      // 16 KB
    float* y0     = (float*)p;     p += (size_t)MM * CC * 4;        // 67 MB
    _Float16* yf  = (_Float16*)p;  p += (size_t)MM * CC * 2;        // 33.5 MB

    // 1. convert inputs to fp16
    tofp16_kernel<<<(MM * CC / 4 + 255) / 256, 256, 0, stream>>>(x, xf, MM * CC / 4);
    tofp16_kernel<<<(3 * CC * CC / 4 + 255) / 256, 256, 0, stream>>>(w_qkv, wqf, 3 * CC * CC / 4);
    tofp16_kernel<<<(CC * CC / 4 + 255) / 256, 256, 0, stream>>>(w_proj, wpf, CC * CC / 4);

    // 2. QKV GEMM with fused focused-feature epilogue -> F (fp16)
    gemm_bt<0><<<dim3(3 * CC / 128, MM / 128), 256, 0, stream>>>(
        xf, wqf, (void*)F, nullptr, 3 * CC);

    // 3. kv / ksum accumulation
    hipMemsetAsync(kvb, 0, (size_t)(BB * HH * 64 * 64 + BB * HH * 64) * 4, stream);
    kv_kernel<<<dim3(8, BB * HH), 256, 0, stream>>>(F, kvb, ksum);

    // 4. attention output
    attn_kernel<<<dim3(HH, BB * (NN / 64)), 256, 0, stream>>>(F, kvb, ksum, y0);

    // 5. depthwise conv + residual -> fp16
    conv_kernel<<<MM, 256, 0, stream>>>(y0, w_dwc, b_dwc, yf);

    // 6. output projection + bias
    gemm_bt<1><<<dim3(CC / 128, MM / 128), 256, 0, stream>>>(
        yf, wpf, d_out, b_proj, CC);
}

// Round 3
// 349.800 us; speedup vs baseline: 2.4364x; 1.3541x over previous
//
#include <hip/hip_runtime.h>
#include <hip/hip_bf16.h>

// Problem constants: B=4, N=4096, C=1024, H=16, d=64
#define BB 4
#define NN 4096
#define CC 1024
#define HH 16
#define MM (BB*NN)          // 16384 token rows
#define EPSF 1e-6f

typedef _Float16 f16x8 __attribute__((ext_vector_type(8)));
typedef float f32x4 __attribute__((ext_vector_type(4)));

__device__ __forceinline__ void gload_lds16(const void* g, void* l) {
    __builtin_amdgcn_global_load_lds(
        (const __attribute__((address_space(1))) void*)g,
        (__attribute__((address_space(3))) void*)l, 16, 0, 0);
}

__device__ __forceinline__ float h2f(short s) {
    return (float)__builtin_bit_cast(_Float16, s);
}

// ---------------------------------------------------------------------------
// fp32 -> fp16, 4 elems/thread
__global__ __launch_bounds__(256)
void tofp16_kernel(const float* __restrict__ src, _Float16* __restrict__ dst, int n4)
{
    int i = blockIdx.x * 256 + threadIdx.x;
    if (i < n4) {
        float4 f = ((const float4*)src)[i];
        short4 pk;
        pk.x = __builtin_bit_cast(short, (_Float16)f.x);
        pk.y = __builtin_bit_cast(short, (_Float16)f.y);
        pk.z = __builtin_bit_cast(short, (_Float16)f.z);
        pk.w = __builtin_bit_cast(short, (_Float16)f.w);
        ((short4*)dst)[i] = pk;
    }
}

// ---------------------------------------------------------------------------
// 256x256-tile fp16 MFMA GEMM, BK=32, 8 waves (2Mx4N), 3 LDS buffers,
// stage-2-ahead with counted vmcnt(4), one barrier per K-tile.
// A: (M x 1024) fp16 row-major.  Bm: (Ncols x 1024) fp16 (B^T layout).
// EPI 0: focused-feature epilogue -> fp16 F ; EPI 1: +bias -> fp32 out.
// LDS swizzle: logical 16B-chunk c8 of row r stored at linear chunk c8^((r>>1)&3);
// applied on the GLOBAL source side for global_load_lds (linear dest), and on
// the ds_read address. Swizzle term is invariant in m/n (16-row steps), so
// frag reads are base + compile-time offsets.

#define STAGE(BUF, KT) do {                                                          \
    _Pragma("unroll")                                                                \
    for (int j_ = 0; j_ < 2; ++j_) {                                                 \
        gload_lds16(gA[j_] + (KT) * 32, (char*)lds + (BUF) * 32768 + lbase[j_]);     \
        gload_lds16(gB[j_] + (KT) * 32, (char*)lds + (BUF) * 32768 + 16384 + lbase[j_]); \
    } } while (0)

#define TILE(KT, CUR, NXT, DOSTAGE, VMSTR) do {                                      \
    if (DOSTAGE) STAGE(NXT, (KT) + 2);                                               \
    const char* Ab_ = (const char*)lds + (CUR) * 32768 + aoff;                       \
    const char* Bb_ = (const char*)lds + (CUR) * 32768 + 16384 + boff;               \
    f16x8 af_[8], bf_[4];                                                            \
    _Pragma("unroll")                                                                \
    for (int m_ = 0; m_ < 8; ++m_) af_[m_] = *(const f16x8*)(Ab_ + m_ * 1024);       \
    _Pragma("unroll")                                                                \
    for (int n_ = 0; n_ < 4; ++n_) bf_[n_] = *(const f16x8*)(Bb_ + n_ * 1024);       \
    __builtin_amdgcn_s_setprio(1);                                                   \
    _Pragma("unroll")                                                                \
    for (int m_ = 0; m_ < 8; ++m_)                                                   \
    _Pragma("unroll")                                                                \
    for (int n_ = 0; n_ < 4; ++n_)                                                   \
        acc[m_][n_] = __builtin_amdgcn_mfma_f32_16x16x32_f16(af_[m_], bf_[n_],       \
                                                             acc[m_][n_], 0, 0, 0); \
    __builtin_amdgcn_s_setprio(0);                                                   \
    asm volatile("s_waitcnt " VMSTR ::: "memory");                                   \
    __builtin_amdgcn_s_barrier();                                                    \
    __builtin_amdgcn_sched_barrier(0);                                               \
} while (0)

template<int EPI>
__global__ __launch_bounds__(512, 2)
void gemm256(const _Float16* __restrict__ A, const _Float16* __restrict__ Bm,
             void* __restrict__ Cout, const float* __restrict__ bias,
             const int Ncols, const int gx)
{
    __shared__ _Float16 lds[3 * 16384];   // 3 bufs x (A 16KB + B 16KB) = 96 KB

    const int tid  = threadIdx.x;
    const int lane = tid & 63;
    const int wid  = tid >> 6;           // 0..7
    const int wm   = wid >> 2;           // 0..1 : 128-row half
    const int wn   = wid & 3;            // 0..3 : 64-col quarter

    // bijective XCD swizzle (nwg % 8 == 0 for both grids)
    const int nwg = gridDim.x;
    const int wg  = blockIdx.x;
    const int sw  = (wg & 7) * (nwg >> 3) + (wg >> 3);
    const int by  = sw / gx, bx = sw - by * gx;
    const int brow = by << 8, bcol = bx << 8;

    // per-thread stage addresses (global side carries the inverse swizzle)
    const _Float16* gA[2]; const _Float16* gB[2]; int lbase[2];
#pragma unroll
    for (int j = 0; j < 2; ++j) {
        int pos = ((wid * 2 + j) << 10) + (lane << 4);   // byte pos in 16KB tile
        int r   = pos >> 6;                              // row 0..255
        int c8  = ((pos >> 4) & 3) ^ ((r >> 1) & 3);     // logical chunk to fetch
        gA[j] = A  + (size_t)(brow + r) * 1024 + c8 * 8;
        gB[j] = Bm + (size_t)(bcol + r) * 1024 + c8 * 8;
        lbase[j] = (wid * 2 + j) << 10;                  // wave-uniform LDS base
    }

    // frag read offsets (swizzle term invariant under +16-row steps)
    const int swz  = (((lane >> 4) ^ ((lane >> 1) & 3)) << 4);
    const int aoff = (wm * 128 + (lane & 15)) * 64 + swz;
    const int boff = (wn * 64  + (lane & 15)) * 64 + swz;

    f32x4 acc[8][4] = {};

    // prologue: stage tiles 0,1; wait tile0 landed (4 of 8 loads may fly)
    STAGE(0, 0);
    STAGE(1, 1);
    asm volatile("s_waitcnt vmcnt(4)" ::: "memory");
    __builtin_amdgcn_s_barrier();
    __builtin_amdgcn_sched_barrier(0);

#pragma unroll 1
    for (int tt = 0; tt < 30; tt += 3) {
        TILE(tt,     0, 2, 1, "vmcnt(4)");
        TILE(tt + 1, 1, 0, 1, "vmcnt(4)");
        TILE(tt + 2, 2, 1, 1, "vmcnt(4)");
    }
    TILE(30, 0, 2, 0, "vmcnt(0)");
    TILE(31, 1, 0, 0, "vmcnt(0)");

    // Epilogue.  D layout: col = lane&15 (+n*16), row = (lane>>4)*4 + reg (+m*16)
    if (EPI == 0) {
        _Float16* Fo = (_Float16*)Cout;
        const bool feat = (bcol + wn * 64) < 2048;   // q,k sections
        const int colb = bcol + wn * 64 + (lane & 15);
#pragma unroll
        for (int m = 0; m < 8; ++m) {
            int rb = brow + wm * 128 + m * 16 + (lane >> 4) * 4;
#pragma unroll
            for (int r = 0; r < 4; ++r) {
                float u3[4]; float ssum = 0.f;
#pragma unroll
                for (int n = 0; n < 4; ++n) {
                    float v = acc[m][n][r];
                    if (feat) {
                        float u = fmaxf(v, 0.f) + EPSF;
                        float c = u * u * u;
                        u3[n] = c; ssum += c;
                    } else u3[n] = v;
                }
                if (feat) {
                    ssum += __shfl_xor(ssum, 1, 16);
                    ssum += __shfl_xor(ssum, 2, 16);
                    ssum += __shfl_xor(ssum, 4, 16);
                    ssum += __shfl_xor(ssum, 8, 16);
                    float inv = 1.0f / ssum;
#pragma unroll
                    for (int n = 0; n < 4; ++n) u3[n] *= inv;
                }
                size_t base = (size_t)(rb + r) * Ncols + colb;
#pragma unroll
                for (int n = 0; n < 4; ++n) Fo[base + n * 16] = (_Float16)u3[n];
            }
        }
    } else {
        float* Oc = (float*)Cout;
        const int colb = bcol + wn * 64 + (lane & 15);
#pragma unroll
        for (int m = 0; m < 8; ++m) {
            int rb = brow + wm * 128 + m * 16 + (lane >> 4) * 4;
#pragma unroll
            for (int r = 0; r < 4; ++r) {
                size_t base = (size_t)(rb + r) * Ncols + colb;
#pragma unroll
                for (int n = 0; n < 4; ++n)
                    Oc[base + n * 16] = acc[m][n][r] + bias[colb + n * 16];
            }
        }
    }
}

// ---------------------------------------------------------------------------
// kv[b,h,dk,dv] = sum_n kf[b,n,h,dk] * v[b,n,h,dv] ; ksum[b,h,dk] = sum_n kf
__global__ __launch_bounds__(256)
void kv_kernel(const _Float16* __restrict__ F, float* __restrict__ kv,
               float* __restrict__ ksum)
{
    int bh = blockIdx.y;                 // 0..63
    int b = bh >> 4, h = bh & 15;
    int seg = blockIdx.x;                // 0..7 over n
    int t = threadIdx.x;
    __shared__ float kf[64][68];
    __shared__ float vf[64][64];
    float acc[16] = {};
    float ks = 0.f;
    int dv = t & 63, dkb = (t >> 6) * 16;
    const _Float16* Fk = F + (size_t)(b * NN) * 3072 + 1024 + h * 64;
    const _Float16* Fv = F + (size_t)(b * NN) * 3072 + 2048 + h * 64;

    for (int tile = 0; tile < 8; ++tile) {
        int n0 = seg * 512 + tile * 64;
        __syncthreads();
#pragma unroll
        for (int i = 0; i < 4; ++i) {
            int idx = t + i * 256;
            int row = idx >> 4, c4 = (idx & 15) * 4;
            short4 kk = *(const short4*)(Fk + (size_t)(n0 + row) * 3072 + c4);
            short4 vv = *(const short4*)(Fv + (size_t)(n0 + row) * 3072 + c4);
            kf[row][c4 + 0] = h2f(kk.x); kf[row][c4 + 1] = h2f(kk.y);
            kf[row][c4 + 2] = h2f(kk.z); kf[row][c4 + 3] = h2f(kk.w);
            vf[row][c4 + 0] = h2f(vv.x); vf[row][c4 + 1] = h2f(vv.y);
            vf[row][c4 + 2] = h2f(vv.z); vf[row][c4 + 3] = h2f(vv.w);
        }
        __syncthreads();
        for (int n = 0; n < 64; ++n) {
            float vv = vf[n][dv];
#pragma unroll
            for (int i = 0; i < 16; ++i)
                acc[i] += kf[n][dkb + i] * vv;
        }
        if (t < 64) {
            for (int n = 0; n < 64; ++n) ks += kf[n][t];
        }
    }
#pragma unroll
    for (int i = 0; i < 16; ++i)
        atomicAdd(&kv[((size_t)bh * 64 + dkb + i) * 64 + dv], acc[i]);
    if (t < 64) atomicAdd(&ksum[bh * 64 + t], ks);
}

// ---------------------------------------------------------------------------
// y0h[b,n,h*64+dv] = fp16( (sum_dk qf*kv) * z )
__global__ __launch_bounds__(256)
void attn_kernel(const _Float16* __restrict__ F, const float* __restrict__ kv,
                 const float* __restrict__ ksum, _Float16* __restrict__ y0h)
{
    int h = blockIdx.x;                  // 0..15
    int cb = blockIdx.y;                 // 0..255
    int b = cb >> 6, chunk = cb & 63;
    int n0 = chunk * 64;
    int t = threadIdx.x;
    int bh = b * HH + h;
    __shared__ float qf[64][68];
    __shared__ float kvs[64 * 64];
    __shared__ float ksm[64];
    __shared__ float zz[64];
    const _Float16* Fq = F + (size_t)(b * NN + n0) * 3072 + h * 64;
#pragma unroll
    for (int i = 0; i < 4; ++i) {
        int idx = t + i * 256;
        int row = idx >> 4, c4 = (idx & 15) * 4;
        short4 qq = *(const short4*)(Fq + (size_t)row * 3072 + c4);
        qf[row][c4 + 0] = h2f(qq.x); qf[row][c4 + 1] = h2f(qq.y);
        qf[row][c4 + 2] = h2f(qq.z); qf[row][c4 + 3] = h2f(qq.w);
        ((float4*)kvs)[idx] = ((const float4*)(kv + (size_t)bh * 4096))[idx];
    }
    if (t < 64) ksm[t] = ksum[bh * 64 + t];
    __syncthreads();
    if (t < 64) {
        float s = 0.f;
        for (int dk = 0; dk < 64; ++dk) s += qf[t][dk] * ksm[dk];
        zz[t] = 1.0f / (s + EPSF);
    }
    __syncthreads();
    int dv = t & 63, nb = t >> 6;
#pragma unroll 4
    for (int i = 0; i < 16; ++i) {
        int nl = nb * 16 + i;
        float a = 0.f;
        for (int dk = 0; dk < 64; ++dk)
            a += qf[nl][dk] * kvs[dk * 64 + dv];
        y0h[(size_t)(b * NN + n0 + nl) * CC + h * 64 + dv] = (_Float16)(a * zz[nl]);
    }
}

// ---------------------------------------------------------------------------
// y = y0 + dwconv3(y0) + b_dwc ; fp16 in/out
__global__ __launch_bounds__(256)
void conv_kernel(const _Float16* __restrict__ y0h, const float* __restrict__ wdwc,
                 const float* __restrict__ bdwc, _Float16* __restrict__ yf)
{
    int gid = blockIdx.x * 256 + threadIdx.x;
    int m = gid >> 8;                    // token row 0..16383
    int c0 = (gid & 255) * 4;
    int n = m & (NN - 1);
    const _Float16* P = y0h + (size_t)m * CC;
    short4 z4; z4.x = z4.y = z4.z = z4.w = 0;
    short4 cu4 = *(const short4*)(P + c0);
    short4 pv4 = (n > 0)      ? *(const short4*)(P - CC + c0) : z4;
    short4 nx4 = (n < NN - 1) ? *(const short4*)(P + CC + c0) : z4;
    float cu[4] = {h2f(cu4.x), h2f(cu4.y), h2f(cu4.z), h2f(cu4.w)};
    float pv[4] = {h2f(pv4.x), h2f(pv4.y), h2f(pv4.z), h2f(pv4.w)};
    float nx[4] = {h2f(nx4.x), h2f(nx4.y), h2f(nx4.z), h2f(nx4.w)};
    short4 pk; short* pks = (short*)&pk;
#pragma unroll
    for (int j = 0; j < 4; ++j) {
        int c = c0 + j;
        float w0 = wdwc[c * 3 + 0], w1 = wdwc[c * 3 + 1], w2 = wdwc[c * 3 + 2];
        float val = cu[j] + pv[j] * w0 + cu[j] * w1 + nx[j] * w2 + bdwc[c];
        pks[j] = __builtin_bit_cast(short, (_Float16)val);
    }
    ((short4*)(yf + (size_t)m * CC))[gid & 255] = pk;
}

// ---------------------------------------------------------------------------
extern "C" void kernel_launch(void* const* d_in, const int* in_sizes, int n_in,
                              void* d_out, int out_size, void* d_ws, size_t ws_size,
                              hipStream_t stream)
{
    const float* x      = (const float*)d_in[0];
    const float* w_qkv  = (const float*)d_in[1];
    const float* w_proj = (const float*)d_in[2];
    const float* b_proj = (const float*)d_in[3];
    const float* w_dwc  = (const float*)d_in[4];
    const float* b_dwc  = (const float*)d_in[5];

    char* p = (char*)d_ws;
    _Float16* xf  = (_Float16*)p;  p += (size_t)MM * CC * 2;        // 33.5 MB
    _Float16* wqf = (_Float16*)p;  p += (size_t)3 * CC * CC * 2;    // 6.3 MB
    _Float16* wpf = (_Float16*)p;  p += (size_t)CC * CC * 2;        // 2.1 MB
    _Float16* F   = (_Float16*)p;  p += (size_t)MM * 3 * CC * 2;    // 100.7 MB
    float* kvb    = (float*)p;     p += (size_t)BB * HH * 64 * 64 * 4; // 1 MB
    float* ksum   = (float*)p;     p += (size_t)BB * HH * 64 * 4;      // 16 KB
    _Float16* y0h = (_Float16*)p;  p += (size_t)MM * CC * 2;        // 33.5 MB
    _Float16* yf  = (_Float16*)p;  p += (size_t)MM * CC * 2;        // 33.5 MB

    // 1. convert inputs to fp16
    tofp16_kernel<<<(MM * CC / 4 + 255) / 256, 256, 0, stream>>>(x, xf, MM * CC / 4);
    tofp16_kernel<<<(3 * CC * CC / 4 + 255) / 256, 256, 0, stream>>>(w_qkv, wqf, 3 * CC * CC / 4);
    tofp16_kernel<<<(CC * CC / 4 + 255) / 256, 256, 0, stream>>>(w_proj, wpf, CC * CC / 4);

    // 2. QKV GEMM with fused focused-feature epilogue -> F (fp16)
    gemm256<0><<<dim3(12 * 64), 512, 0, stream>>>(xf, wqf, (void*)F, nullptr, 3072, 12);

    // 3. kv / ksum accumulation
    hipMemsetAsync(kvb, 0, (size_t)(BB * HH * 64 * 64 + BB * HH * 64) * 4, stream);
    kv_kernel<<<dim3(8, BB * HH), 256, 0, stream>>>(F, kvb, ksum);

    // 4. attention output -> fp16
    attn_kernel<<<dim3(HH, BB * (NN / 64)), 256, 0, stream>>>(F, kvb, ksum, y0h);

    // 5. depthwise conv + residual -> fp16
    conv_kernel<<<MM, 256, 0, stream>>>(y0h, w_dwc, b_dwc, yf);

    // 6. output projection + bias
    gemm256<1><<<dim3(4 * 64), 512, 0, stream>>>(yf, wpf, d_out, b_proj, 1024, 4);
}

// Round 5
// 224.222 us; speedup vs baseline: 3.8009x; 1.5601x over previous
//
#include <hip/hip_runtime.h>
#include <hip/hip_bf16.h>

// Problem constants: B=4, N=4096, C=1024, H=16, d=64
#define BB 4
#define NN 4096
#define CC 1024
#define HH 16
#define MM (BB*NN)          // 16384 token rows
#define EPSF 1e-6f

typedef _Float16 f16x8 __attribute__((ext_vector_type(8)));
typedef float f32x4 __attribute__((ext_vector_type(4)));

__device__ __forceinline__ void gload_lds16(const void* g, void* l) {
    __builtin_amdgcn_global_load_lds(
        (const __attribute__((address_space(1))) void*)g,
        (__attribute__((address_space(3))) void*)l, 16, 0, 0);
}

__device__ __forceinline__ float h2f(short s) {
    return (float)__builtin_bit_cast(_Float16, s);
}

// ---------------------------------------------------------------------------
// fp32 -> fp16, 4 elems/thread
__global__ __launch_bounds__(256)
void tofp16_kernel(const float* __restrict__ src, _Float16* __restrict__ dst, int n4)
{
    int i = blockIdx.x * 256 + threadIdx.x;
    if (i < n4) {
        float4 f = ((const float4*)src)[i];
        short4 pk;
        pk.x = __builtin_bit_cast(short, (_Float16)f.x);
        pk.y = __builtin_bit_cast(short, (_Float16)f.y);
        pk.z = __builtin_bit_cast(short, (_Float16)f.z);
        pk.w = __builtin_bit_cast(short, (_Float16)f.w);
        ((short4*)dst)[i] = pk;
    }
}

// ---------------------------------------------------------------------------
// 256x256-tile fp16 MFMA GEMM, BK=32, 8 waves (2Mx4N), 3 LDS buffers,
// stage-2-ahead with counted vmcnt(4), one barrier per K-tile.
// EPI 0 (QKV): q cols -> Fq natural (stride 1024) with feature map;
//              k cols -> feature map then TRANSPOSED to Kt[bh][dk][n];
//              v cols -> TRANSPOSED to Vt[bh][dv][n].
// EPI 1 (proj): +bias -> fp32 out.

#define STAGE(BUF, KT) do {                                                          \
    _Pragma("unroll")                                                                \
    for (int j_ = 0; j_ < 2; ++j_) {                                                 \
        gload_lds16(gA[j_] + (KT) * 32, (char*)lds + (BUF) * 32768 + lbase[j_]);     \
        gload_lds16(gB[j_] + (KT) * 32, (char*)lds + (BUF) * 32768 + 16384 + lbase[j_]); \
    } } while (0)

#define TILE(KT, CUR, NXT, DOSTAGE, VMSTR) do {                                      \
    if (DOSTAGE) STAGE(NXT, (KT) + 2);                                               \
    const char* Ab_ = (const char*)lds + (CUR) * 32768 + aoff;                       \
    const char* Bb_ = (const char*)lds + (CUR) * 32768 + 16384 + boff;               \
    f16x8 af_[8], bf_[4];                                                            \
    _Pragma("unroll")                                                                \
    for (int m_ = 0; m_ < 8; ++m_) af_[m_] = *(const f16x8*)(Ab_ + m_ * 1024);       \
    _Pragma("unroll")                                                                \
    for (int n_ = 0; n_ < 4; ++n_) bf_[n_] = *(const f16x8*)(Bb_ + n_ * 1024);       \
    __builtin_amdgcn_s_setprio(1);                                                   \
    _Pragma("unroll")                                                                \
    for (int m_ = 0; m_ < 8; ++m_)                                                   \
    _Pragma("unroll")                                                                \
    for (int n_ = 0; n_ < 4; ++n_)                                                   \
        acc[m_][n_] = __builtin_amdgcn_mfma_f32_16x16x32_f16(af_[m_], bf_[n_],       \
                                                             acc[m_][n_], 0, 0, 0); \
    __builtin_amdgcn_s_setprio(0);                                                   \
    asm volatile("s_waitcnt " VMSTR ::: "memory");                                   \
    __builtin_amdgcn_s_barrier();                                                    \
    __builtin_amdgcn_sched_barrier(0);                                               \
} while (0)

template<int EPI>
__global__ __launch_bounds__(512, 2)
void gemm256(const _Float16* __restrict__ A, const _Float16* __restrict__ Bm,
             void* __restrict__ Cout, _Float16* __restrict__ Kt,
             _Float16* __restrict__ Vt, const float* __restrict__ bias,
             const int Ncols, const int gx)
{
    __shared__ _Float16 lds[3 * 16384];   // 96 KB

    const int tid  = threadIdx.x;
    const int lane = tid & 63;
    const int wid  = tid >> 6;           // 0..7
    const int wm   = wid >> 2;           // 0..1 : 128-row half
    const int wn   = wid & 3;            // 0..3 : 64-col quarter

    const int nwg = gridDim.x;
    const int wg  = blockIdx.x;
    const int sw  = (wg & 7) * (nwg >> 3) + (wg >> 3);
    const int by  = sw / gx, bx = sw - by * gx;
    const int brow = by << 8, bcol = bx << 8;

    const _Float16* gA[2]; const _Float16* gB[2]; int lbase[2];
#pragma unroll
    for (int j = 0; j < 2; ++j) {
        int pos = ((wid * 2 + j) << 10) + (lane << 4);
        int r   = pos >> 6;
        int c8  = ((pos >> 4) & 3) ^ ((r >> 1) & 3);
        gA[j] = A  + (size_t)(brow + r) * 1024 + c8 * 8;
        gB[j] = Bm + (size_t)(bcol + r) * 1024 + c8 * 8;
        lbase[j] = (wid * 2 + j) << 10;
    }

    const int swz  = (((lane >> 4) ^ ((lane >> 1) & 3)) << 4);
    const int aoff = (wm * 128 + (lane & 15)) * 64 + swz;
    const int boff = (wn * 64  + (lane & 15)) * 64 + swz;

    f32x4 acc[8][4] = {};

    STAGE(0, 0);
    STAGE(1, 1);
    asm volatile("s_waitcnt vmcnt(4)" ::: "memory");
    __builtin_amdgcn_s_barrier();
    __builtin_amdgcn_sched_barrier(0);

#pragma unroll 1
    for (int tt = 0; tt < 30; tt += 3) {
        TILE(tt,     0, 2, 1, "vmcnt(4)");
        TILE(tt + 1, 1, 0, 1, "vmcnt(4)");
        TILE(tt + 2, 2, 1, 1, "vmcnt(4)");
    }
    TILE(30, 0, 2, 0, "vmcnt(0)");
    TILE(31, 1, 0, 0, "vmcnt(0)");

    if (EPI == 0) {
        const int sec = bcol >> 10;          // 0=q, 1=k, 2=v
        const bool feat = (sec < 2);
        // in-place feature map (relu+eps)^3, renormalized over head's 64 cols
        if (feat) {
#pragma unroll
            for (int m = 0; m < 8; ++m)
#pragma unroll
                for (int r = 0; r < 4; ++r) {
                    float u[4]; float ssum = 0.f;
#pragma unroll
                    for (int n = 0; n < 4; ++n) {
                        float uu = fmaxf(acc[m][n][r], 0.f) + EPSF;
                        float c = uu * uu * uu;
                        u[n] = c; ssum += c;
                    }
                    ssum += __shfl_xor(ssum, 1, 16);
                    ssum += __shfl_xor(ssum, 2, 16);
                    ssum += __shfl_xor(ssum, 4, 16);
                    ssum += __shfl_xor(ssum, 8, 16);
                    float inv = 1.0f / ssum;
#pragma unroll
                    for (int n = 0; n < 4; ++n) acc[m][n][r] = u[n] * inv;
                }
        }
        if (sec == 0) {
            _Float16* Fo = (_Float16*)Cout;
            const int colb = bcol + wn * 64 + (lane & 15);
#pragma unroll
            for (int m = 0; m < 8; ++m) {
                int rb = brow + wm * 128 + m * 16 + (lane >> 4) * 4;
#pragma unroll
                for (int r = 0; r < 4; ++r) {
                    size_t base = (size_t)(rb + r) * 1024 + colb;
#pragma unroll
                    for (int n = 0; n < 4; ++n)
                        Fo[base + n * 16] = (_Float16)acc[m][n][r];
                }
            }
        } else {
            _Float16* T = (sec == 1) ? Kt : Vt;
            const int b   = brow >> 12;
            const int hb  = ((bcol & 1023) >> 6) + wn;
            const int bh  = b * 16 + hb;
            const int n0  = (brow & 4095) + wm * 128;
            char* st = (char*)lds + wid * 8704;       // 64 dk x 68 tok fp16
            const int p = lane & 15, q2 = lane >> 4;
#pragma unroll
            for (int c2 = 0; c2 < 2; ++c2) {
#pragma unroll
                for (int m = 0; m < 4; ++m) {
                    int mm = c2 * 4 + m;
                    int tokc = m * 16 + q2 * 4;
#pragma unroll
                    for (int n = 0; n < 4; ++n) {
                        short4 pk;
                        pk.x = __builtin_bit_cast(short, (_Float16)acc[mm][n][0]);
                        pk.y = __builtin_bit_cast(short, (_Float16)acc[mm][n][1]);
                        pk.z = __builtin_bit_cast(short, (_Float16)acc[mm][n][2]);
                        pk.w = __builtin_bit_cast(short, (_Float16)acc[mm][n][3]);
                        int dk = n * 16 + p;
                        *(short4*)(st + dk * 136 + tokc * 2) = pk;
                    }
                }
#pragma unroll
                for (int it = 0; it < 16; ++it) {
                    int dk = it * 4 + q2;
                    short4 v4 = *(const short4*)(st + dk * 136 + p * 8);
                    *(short4*)(T + ((size_t)(bh * 64 + dk)) * 4096 + n0 + c2 * 64 + p * 4) = v4;
                }
            }
        }
    } else {
        float* Oc = (float*)Cout;
        const int colb = bcol + wn * 64 + (lane & 15);
#pragma unroll
        for (int m = 0; m < 8; ++m) {
            int rb = brow + wm * 128 + m * 16 + (lane >> 4) * 4;
#pragma unroll
            for (int r = 0; r < 4; ++r) {
                size_t base = (size_t)(rb + r) * Ncols + colb;
#pragma unroll
                for (int n = 0; n < 4; ++n)
                    Oc[base + n * 16] = acc[m][n][r] + bias[colb + n * 16];
            }
        }
    }
}

// ---------------------------------------------------------------------------
// Partial kvT: per (bh, kseg): kvp[kseg][bh][dv][dk] = sum_{n in seg} Vt[dv][n]*Kt[dk][n]
// ksump[kseg][bh][dk] = sum_{n in seg} Kt[dk][n]
__global__ __launch_bounds__(256)
void kv_mfma(const _Float16* __restrict__ Kt, const _Float16* __restrict__ Vt,
             float* __restrict__ kvp, float* __restrict__ ksump)
{
    __shared__ float red[4][64][64];
    __shared__ float ksr[4][64];
    int bx = blockIdx.x;                 // 0..255
    int bh = bx >> 2, kseg = bx & 3;
    int tid = threadIdx.x;
    int w = tid >> 6, lane = tid & 63, p = lane & 15, q = lane >> 4;
    const _Float16* Vb = Vt + (size_t)bh * 64 * 4096;
    const _Float16* Kb = Kt + (size_t)bh * 64 * 4096;
    f32x4 acc[4][4] = {};
    float ksp[4] = {0.f, 0.f, 0.f, 0.f};
    int kbase = kseg * 1024 + w * 256 + q * 8;
#pragma unroll 1
    for (int ks = 0; ks < 8; ++ks) {
        int kb = kbase + ks * 32;
        f16x8 af[4], bf[4];
#pragma unroll
        for (int m = 0; m < 4; ++m)
            af[m] = *(const f16x8*)(Vb + (size_t)(m * 16 + p) * 4096 + kb);
#pragma unroll
        for (int n = 0; n < 4; ++n) {
            bf[n] = *(const f16x8*)(Kb + (size_t)(n * 16 + p) * 4096 + kb);
#pragma unroll
            for (int j = 0; j < 8; ++j) ksp[n] += (float)bf[n][j];
        }
#pragma unroll
        for (int m = 0; m < 4; ++m)
#pragma unroll
            for (int n = 0; n < 4; ++n)
                acc[m][n] = __builtin_amdgcn_mfma_f32_16x16x32_f16(
                    af[m], bf[n], acc[m][n], 0, 0, 0);
    }
#pragma unroll
    for (int n = 0; n < 4; ++n) {
        ksp[n] += __shfl_xor(ksp[n], 16);
        ksp[n] += __shfl_xor(ksp[n], 32);
    }
    if (q == 0)
#pragma unroll
        for (int n = 0; n < 4; ++n) ksr[w][n * 16 + p] = ksp[n];
#pragma unroll
    for (int m = 0; m < 4; ++m)
#pragma unroll
        for (int n = 0; n < 4; ++n)
            *(f32x4*)&red[w][n * 16 + p][m * 16 + q * 4] = acc[m][n];
    __syncthreads();
    int dv = tid & 63, dkb = (tid >> 6) * 16;
    float* ko = kvp + ((size_t)(kseg * 64 + bh)) * 4096;
    f32x4 o[4];
#pragma unroll
    for (int i = 0; i < 16; ++i) {
        float s = red[0][dkb + i][dv] + red[1][dkb + i][dv]
                + red[2][dkb + i][dv] + red[3][dkb + i][dv];
        o[i >> 2][i & 3] = s;
    }
#pragma unroll
    for (int i = 0; i < 4; ++i)
        *(f32x4*)(ko + dv * 64 + dkb + i * 4) = o[i];
    if (tid < 64)
        ksump[(size_t)(kseg * 64 + bh) * 64 + tid] =
            ksr[0][tid] + ksr[1][tid] + ksr[2][tid] + ksr[3][tid];
}

// ---------------------------------------------------------------------------
// Fold 4 k-segment partials: kvT fp16 [bh][dv][dk], ksum f32 [bh][dk]
__global__ __launch_bounds__(256)
void kv_reduce(const float* __restrict__ kvp, const float* __restrict__ ksump,
               _Float16* __restrict__ kvT, float* __restrict__ ksum)
{
    int idx = blockIdx.x * 256 + threadIdx.x;        // 0..262143
    float s = kvp[idx] + kvp[262144 + idx] + kvp[2 * 262144 + idx] + kvp[3 * 262144 + idx];
    kvT[idx] = (_Float16)s;
    if (idx < 4096)
        ksum[idx] = ksump[idx] + ksump[4096 + idx] + ksump[2 * 4096 + idx] + ksump[3 * 4096 + idx];
}

// ---------------------------------------------------------------------------
// Fused attention-out + depthwise conv + residual -> yf (fp16)
// block = (b, h, 256-token chunk); 4 waves x 64 tokens.
__global__ __launch_bounds__(256)
void attn_conv(const _Float16* __restrict__ Fq, const _Float16* __restrict__ kvT,
               const float* __restrict__ ksum, const float* __restrict__ wdwc,
               const float* __restrict__ bdwc, _Float16* __restrict__ yf)
{
    __shared__ _Float16 ybuf[258][68];
    __shared__ float kslds[64];
    int blk = blockIdx.x;
    int b = blk >> 8, h = (blk >> 4) & 15, chunk = blk & 15;
    int bh = b * 16 + h;
    int tid = threadIdx.x, w = tid >> 6, lane = tid & 63, p = lane & 15, q = lane >> 4;
    if (tid < 64) kslds[tid] = ksum[bh * 64 + tid];
    const _Float16* kvb = kvT + (size_t)bh * 4096;
    f16x8 bf[2][4];
#pragma unroll
    for (int kst = 0; kst < 2; ++kst)
#pragma unroll
        for (int n = 0; n < 4; ++n)
            bf[kst][n] = *(const f16x8*)(kvb + (n * 16 + p) * 64 + kst * 32 + q * 8);
    __syncthreads();

    int tok0 = chunk * 256 + w * 64;
    const size_t rowbase = (size_t)(b * 4096 + tok0);
    // z for token row tok0+lane
    f16x8 qr[8];
#pragma unroll
    for (int i = 0; i < 8; ++i)
        qr[i] = *(const f16x8*)(Fq + (rowbase + lane) * 1024 + h * 64 + i * 8);
    float s = 0.f;
#pragma unroll
    for (int i = 0; i < 8; ++i)
#pragma unroll
        for (int j = 0; j < 8; ++j)
            s += (float)qr[i][j] * kslds[i * 8 + j];
    float z = 1.0f / (s + EPSF);

    f32x4 acc[4][4] = {};
#pragma unroll
    for (int kst = 0; kst < 2; ++kst) {
        f16x8 af[4];
#pragma unroll
        for (int m = 0; m < 4; ++m)
            af[m] = *(const f16x8*)(Fq + (rowbase + m * 16 + p) * 1024 + h * 64 + kst * 32 + q * 8);
#pragma unroll
        for (int m = 0; m < 4; ++m)
#pragma unroll
            for (int n = 0; n < 4; ++n)
                acc[m][n] = __builtin_amdgcn_mfma_f32_16x16x32_f16(
                    af[m], bf[kst][n], acc[m][n], 0, 0, 0);
    }
#pragma unroll
    for (int m = 0; m < 4; ++m)
#pragma unroll
        for (int r = 0; r < 4; ++r) {
            float zz = __shfl(z, m * 16 + q * 4 + r);
            int row = 1 + w * 64 + m * 16 + q * 4 + r;
#pragma unroll
            for (int n = 0; n < 4; ++n)
                ybuf[row][n * 16 + p] = (_Float16)(acc[m][n][r] * zz);
        }
    // halo rows (recompute attn for tokens chunk*256-1 and chunk*256+256)
    if (w == 0) {
        float val = 0.f;
        if (chunk > 0) {
            int t = chunk * 256 - 1;
            float sd = 0.f, sz = 0.f;
#pragma unroll
            for (int i = 0; i < 8; ++i) {
                f16x8 qq = *(const f16x8*)(Fq + ((size_t)(b * 4096 + t)) * 1024 + h * 64 + i * 8);
                f16x8 kk = *(const f16x8*)(kvb + lane * 64 + i * 8);
#pragma unroll
                for (int j = 0; j < 8; ++j) {
                    sd += (float)qq[j] * (float)kk[j];
                    sz += (float)qq[j] * kslds[i * 8 + j];
                }
            }
            val = sd / (sz + EPSF);
        }
        ybuf[0][lane] = (_Float16)val;
    }
    if (w == 3) {
        float val = 0.f;
        if (chunk < 15) {
            int t = chunk * 256 + 256;
            float sd = 0.f, sz = 0.f;
#pragma unroll
            for (int i = 0; i < 8; ++i) {
                f16x8 qq = *(const f16x8*)(Fq + ((size_t)(b * 4096 + t)) * 1024 + h * 64 + i * 8);
                f16x8 kk = *(const f16x8*)(kvb + lane * 64 + i * 8);
#pragma unroll
                for (int j = 0; j < 8; ++j) {
                    sd += (float)qq[j] * (float)kk[j];
                    sz += (float)qq[j] * kslds[i * 8 + j];
                }
            }
            val = sd / (sz + EPSF);
        }
        ybuf[257][lane] = (_Float16)val;
    }
    __syncthreads();
    // conv + residual + write
    int dv = lane;
    int c = h * 64 + dv;
    float w0 = wdwc[c * 3 + 0], w1 = wdwc[c * 3 + 1], w2 = wdwc[c * 3 + 2];
    float bb = bdwc[c];
#pragma unroll 4
    for (int it = 0; it < 64; ++it) {
        int tok = it * 4 + w;
        float ym = (float)ybuf[tok][dv];
        float yc = (float)ybuf[tok + 1][dv];
        float yp = (float)ybuf[tok + 2][dv];
        float val = yc + w0 * ym + w1 * yc + w2 * yp + bb;
        yf[((size_t)(b * 4096 + chunk * 256 + tok)) * 1024 + c] = (_Float16)val;
    }
}

// ---------------------------------------------------------------------------
extern "C" void kernel_launch(void* const* d_in, const int* in_sizes, int n_in,
                              void* d_out, int out_size, void* d_ws, size_t ws_size,
                              hipStream_t stream)
{
    const float* x      = (const float*)d_in[0];
    const float* w_qkv  = (const float*)d_in[1];
    const float* w_proj = (const float*)d_in[2];
    const float* b_proj = (const float*)d_in[3];
    const float* w_dwc  = (const float*)d_in[4];
    const float* b_dwc  = (const float*)d_in[5];

    char* p = (char*)d_ws;
    _Float16* xf   = (_Float16*)p;  p += (size_t)MM * CC * 2;         // 33.5 MB
    _Float16* wqf  = (_Float16*)p;  p += (size_t)3 * CC * CC * 2;     // 6.3 MB
    _Float16* wpf  = (_Float16*)p;  p += (size_t)CC * CC * 2;         // 2.1 MB
    _Float16* Fq   = (_Float16*)p;  p += (size_t)MM * CC * 2;         // 33.5 MB
    _Float16* Kt   = (_Float16*)p;  p += (size_t)64 * 64 * NN * 2;    // 33.5 MB
    _Float16* Vt   = (_Float16*)p;  p += (size_t)64 * 64 * NN * 2;    // 33.5 MB
    float*    kvp  = (float*)p;     p += (size_t)4 * 64 * 4096 * 4;   // 4.2 MB
    float*    ksump= (float*)p;     p += (size_t)4 * 64 * 64 * 4;     // 64 KB
    _Float16* kvT  = (_Float16*)p;  p += (size_t)64 * 4096 * 2;       // 0.5 MB
    float*    ksum = (float*)p;     p += (size_t)64 * 64 * 4;         // 16 KB
    _Float16* yf   = (_Float16*)p;  p += (size_t)MM * CC * 2;         // 33.5 MB

    // 1. inputs to fp16
    tofp16_kernel<<<(MM * CC / 4 + 255) / 256, 256, 0, stream>>>(x, xf, MM * CC / 4);
    tofp16_kernel<<<(3 * CC * CC / 4 + 255) / 256, 256, 0, stream>>>(w_qkv, wqf, 3 * CC * CC / 4);
    tofp16_kernel<<<(CC * CC / 4 + 255) / 256, 256, 0, stream>>>(w_proj, wpf, CC * CC / 4);

    // 2. QKV GEMM, feature-map epilogue; q natural, k/v transposed per head
    gemm256<0><<<dim3(12 * 64), 512, 0, stream>>>(
        xf, wqf, (void*)Fq, Kt, Vt, nullptr, 3072, 12);

    // 3. kv partials (MFMA) + fold
    kv_mfma<<<256, 256, 0, stream>>>(Kt, Vt, kvp, ksump);
    kv_reduce<<<1024, 256, 0, stream>>>(kvp, ksump, kvT, ksum);

    // 4. attention output + depthwise conv + residual -> yf
    attn_conv<<<BB * HH * 16, 256, 0, stream>>>(Fq, kvT, ksum, w_dwc, b_dwc, yf);

    // 5. output projection + bias
    gemm256<1><<<dim3(4 * 64), 512, 0, stream>>>(
        yf, wpf, d_out, nullptr, nullptr, b_proj, 1024, 4);
}